// Round 26
// baseline (152.044 us; speedup 1.0000x reference)
//
#include <hip/hip_runtime.h>
#include <hip/hip_bf16.h>
#include <cstdint>
#include <cstddef>

#define BB 8
#define SS 8192
#define DD 64
#define HH 8
#define NB 128
#define NCHUNK 128   /* S / 64 */
#define CHUNKS 1024  /* H * NB */

typedef __attribute__((ext_vector_type(8))) short bf16x8;
typedef __attribute__((ext_vector_type(4))) float f32x4;

__device__ __forceinline__ unsigned short f2b(float x) {
  __hip_bfloat16 hb = __float2bfloat16(x);
  union { __hip_bfloat16 h; unsigned short u; } c; c.h = hb;
  return c.u;
}
__device__ __forceinline__ float b2f(unsigned short h) {
  union { unsigned int u; float f; } c; c.u = ((unsigned int)h) << 16;
  return c.f;
}

// ---------------------------------------------------------------------------
// Kernel 0: prep — qhat (normalized bf16), snorm (f32), vb (bf16), and the
// hi/lo bf16 split of raw qk (qhi/qlo) for the hash MFMA screen.
// ---------------------------------------------------------------------------
__global__ __launch_bounds__(256) void prep_kernel(const float* __restrict__ qk,
                                                   const float* __restrict__ v,
                                                   unsigned short* __restrict__ qhat,
                                                   unsigned short* __restrict__ vb,
                                                   unsigned short* __restrict__ qhi,
                                                   unsigned short* __restrict__ qlo,
                                                   float* __restrict__ snorm) {
  const int idx = blockIdx.x * 256 + threadIdx.x;
  const int row = idx >> 3, seg = idx & 7;
  const size_t base = (size_t)row * DD + seg * 8;

  float4 a0 = ((const float4*)(qk + base))[0];
  float4 a1 = ((const float4*)(qk + base))[1];
  float vals[8] = {a0.x, a0.y, a0.z, a0.w, a1.x, a1.y, a1.z, a1.w};
  float ssq = 0.f;
#pragma unroll
  for (int k = 0; k < 8; ++k) ssq += vals[k] * vals[k];
  ssq += __shfl_xor(ssq, 1);
  ssq += __shfl_xor(ssq, 2);
  ssq += __shfl_xor(ssq, 4);
  const float r = rsqrtf(ssq + 1e-6f);
  const float sn = (ssq + 1e-6f) * r;  // sqrt(ssq + eps)
  uint4 qo;
  unsigned int* qp = (unsigned int*)&qo;
#pragma unroll
  for (int k = 0; k < 4; ++k)
    qp[k] = (unsigned int)f2b(vals[2 * k] * r) | ((unsigned int)f2b(vals[2 * k + 1] * r) << 16);
  *(uint4*)(qhat + base) = qo;
  if (seg == 0) snorm[row] = sn;

  uint4 ho, lo4;
  unsigned int* hp = (unsigned int*)&ho;
  unsigned int* lp = (unsigned int*)&lo4;
#pragma unroll
  for (int k = 0; k < 4; ++k) {
    const unsigned short h0 = f2b(vals[2 * k]);
    const unsigned short h1 = f2b(vals[2 * k + 1]);
    const unsigned short l0 = f2b(vals[2 * k] - b2f(h0));
    const unsigned short l1 = f2b(vals[2 * k + 1] - b2f(h1));
    hp[k] = (unsigned int)h0 | ((unsigned int)h1 << 16);
    lp[k] = (unsigned int)l0 | ((unsigned int)l1 << 16);
  }
  *(uint4*)(qhi + base) = ho;
  *(uint4*)(qlo + base) = lo4;

  float4 v0 = ((const float4*)(v + base))[0];
  float4 v1 = ((const float4*)(v + base))[1];
  float vv[8] = {v0.x, v0.y, v0.z, v0.w, v1.x, v1.y, v1.z, v1.w};
  uint4 vo;
  unsigned int* vp = (unsigned int*)&vo;
#pragma unroll
  for (int k = 0; k < 4; ++k)
    vp[k] = (unsigned int)f2b(vv[2 * k]) | ((unsigned int)f2b(vv[2 * k + 1]) << 16);
  *(uint4*)(vb + base) = vo;
}

// ---------------------------------------------------------------------------
// Kernel 0b: transpose rot -> rotT (f32 [512][64]) + hi/lo bf16 split
// rhiT/rloT ([512][64]). Grid 8 x 256, one 64x64 tile per block.
// ---------------------------------------------------------------------------
__global__ __launch_bounds__(256) void rott_kernel(const float* __restrict__ rot,
                                                   float* __restrict__ rotT,
                                                   unsigned short* __restrict__ rhiT,
                                                   unsigned short* __restrict__ rloT) {
  __shared__ float tile[64][68];
  const int tid = threadIdx.x;
  const int hi0 = blockIdx.x * 64;
#pragma unroll
  for (int rep = 0; rep < 4; ++rep) {
    const int j = rep * 256 + tid;
    const int f = j >> 4, c4 = (j & 15) * 4;
    const float4 vv = *(const float4*)(rot + (size_t)f * (HH * 64) + hi0 + c4);
    *(float4*)&tile[f][c4] = vv;
  }
  __syncthreads();
#pragma unroll
  for (int rep = 0; rep < 4; ++rep) {
    const int j = rep * 256 + tid;
    const int c = j >> 4, f4 = (j & 15) * 4;
    float4 o;
    o.x = tile[f4 + 0][c];
    o.y = tile[f4 + 1][c];
    o.z = tile[f4 + 2][c];
    o.w = tile[f4 + 3][c];
    *(float4*)(rotT + (size_t)(hi0 + c) * 64 + f4) = o;
    const float xs[4] = {o.x, o.y, o.z, o.w};
    unsigned int hpack[2], lpack[2];
#pragma unroll
    for (int e = 0; e < 2; ++e) {
      const unsigned short h0 = f2b(xs[2 * e]);
      const unsigned short h1 = f2b(xs[2 * e + 1]);
      const unsigned short l0 = f2b(xs[2 * e] - b2f(h0));
      const unsigned short l1 = f2b(xs[2 * e + 1] - b2f(h1));
      hpack[e] = (unsigned int)h0 | ((unsigned int)h1 << 16);
      lpack[e] = (unsigned int)l0 | ((unsigned int)l1 << 16);
    }
    uint2 hv; hv.x = hpack[0]; hv.y = hpack[1];
    uint2 lv; lv.x = lpack[0]; lv.y = lpack[1];
    *(uint2*)&rhiT[(size_t)(hi0 + c) * 64 + f4] = hv;
    *(uint2*)&rloT[(size_t)(hi0 + c) * 64 + f4] = lv;
  }
}

// ---------------------------------------------------------------------------
// Kernel 1: LSH hash — transposed MFMA screen with manual cross-h double
// buffering (unchanged from R20-R24). Exact-f32 fallback (bit-identical
// serial chain) when >=2 candidates within TH of the max. Grid (512, 1, 2).
// ---------------------------------------------------------------------------
#define TH 0.015625f

#define LOAD_ROT(HV, RH0, RH1, RL0, RL1)                                   \
  {                                                                        \
    _Pragma("unroll") for (int n = 0; n < 4; ++n) {                        \
      const size_t roff = (size_t)((HV) * 64 + 16 * n + r16) * DD;         \
      RH0[n] = *(const bf16x8*)(rhiT + roff + g * 8);                      \
      RH1[n] = *(const bf16x8*)(rhiT + roff + 32 + g * 8);                 \
      RL0[n] = *(const bf16x8*)(rloT + roff + g * 8);                      \
      RL1[n] = *(const bf16x8*)(rloT + roff + 32 + g * 8);                 \
    }                                                                      \
  }

#define COMPUTE_H(HV, RH0, RH1, RL0, RL1)                                  \
  {                                                                        \
    const int h = (HV);                                                    \
    f32x4 acc[2][4];                                                       \
    _Pragma("unroll") for (int grp = 0; grp < 2; ++grp)                    \
      _Pragma("unroll") for (int n = 0; n < 4; ++n)                        \
        acc[grp][n] = (f32x4){0.f, 0.f, 0.f, 0.f};                         \
    _Pragma("unroll") for (int n = 0; n < 4; ++n) {                        \
      _Pragma("unroll") for (int grp = 0; grp < 2; ++grp) {                \
        acc[grp][n] = __builtin_amdgcn_mfma_f32_16x16x32_bf16(RH0[n], qh0[grp], acc[grp][n], 0, 0, 0); \
        acc[grp][n] = __builtin_amdgcn_mfma_f32_16x16x32_bf16(RL0[n], qh0[grp], acc[grp][n], 0, 0, 0); \
        acc[grp][n] = __builtin_amdgcn_mfma_f32_16x16x32_bf16(RH0[n], ql0[grp], acc[grp][n], 0, 0, 0); \
        acc[grp][n] = __builtin_amdgcn_mfma_f32_16x16x32_bf16(RH1[n], qh1[grp], acc[grp][n], 0, 0, 0); \
        acc[grp][n] = __builtin_amdgcn_mfma_f32_16x16x32_bf16(RL1[n], qh1[grp], acc[grp][n], 0, 0, 0); \
        acc[grp][n] = __builtin_amdgcn_mfma_f32_16x16x32_bf16(RH1[n], ql1[grp], acc[grp][n], 0, 0, 0); \
      }                                                                    \
    }                                                                      \
    _Pragma("unroll") for (int grp = 0; grp < 2; ++grp) {                  \
      float bv = 0.f;                                                      \
      _Pragma("unroll") for (int n = 0; n < 4; ++n)                        \
        _Pragma("unroll") for (int i = 0; i < 4; ++i)                      \
          bv = fmaxf(bv, fabsf(acc[grp][n][i]));                           \
      bv = fmaxf(bv, __shfl_xor(bv, 16));                                  \
      bv = fmaxf(bv, __shfl_xor(bv, 32));                                  \
      int mi = 9999;                                                       \
      _Pragma("unroll") for (int n = 0; n < 4; ++n)                        \
        _Pragma("unroll") for (int i = 0; i < 4; ++i) {                    \
          const float vv = acc[grp][n][i];                                 \
          const int c = 16 * n + 4 * g + i;                                \
          const int idx = (vv < 0.f) ? (c + 64) : c;                       \
          if (fabsf(vv) == bv && idx < mi) mi = idx;                       \
        }                                                                  \
      {                                                                    \
        const int o1 = __shfl_xor(mi, 16); mi = (o1 < mi) ? o1 : mi;       \
        const int o2 = __shfl_xor(mi, 32); mi = (o2 < mi) ? o2 : mi;       \
      }                                                                    \
      unsigned int pmask = 0, nmask = 0;                                   \
      _Pragma("unroll") for (int n = 0; n < 4; ++n)                        \
        _Pragma("unroll") for (int i = 0; i < 4; ++i) {                    \
          if (acc[grp][n][i] >= bv - TH) pmask |= 1u << (n * 4 + i);       \
          if (-acc[grp][n][i] >= bv - TH) nmask |= 1u << (n * 4 + i);      \
        }                                                                  \
      int cnt = __popc(pmask) + __popc(nmask);                             \
      cnt += __shfl_xor(cnt, 16);                                          \
      cnt += __shfl_xor(cnt, 32);                                          \
      int bi = mi;                                                         \
      if (cnt >= 2) {                                                      \
        const float* qrowp = qk + (size_t)(rowbase + grp * 16 + r16) * DD; \
        float mv = -3.4e38f;                                               \
        int fmi = 9999;                                                    \
        unsigned int am = pmask | nmask;                                   \
        while (am) {                                                       \
          const int bitp = __ffs(am) - 1;                                  \
          am &= am - 1;                                                    \
          const int n = bitp >> 2, i = bitp & 3;                           \
          const int c = 16 * n + 4 * g + i;                                \
          const float* rrow = rotT + (size_t)(h * 64 + c) * DD;            \
          float d = 0.f;                                                   \
          _Pragma("unroll") for (int f4 = 0; f4 < 16; ++f4) {              \
            const float4 qv = *(const float4*)(qrowp + 4 * f4);            \
            const float4 rv = *(const float4*)(rrow + 4 * f4);             \
            d = fmaf(qv.x, rv.x, d);                                       \
            d = fmaf(qv.y, rv.y, d);                                       \
            d = fmaf(qv.z, rv.z, d);                                       \
            d = fmaf(qv.w, rv.w, d);                                       \
          }                                                                \
          const bool cp = (pmask >> bitp) & 1;                             \
          const bool cn = (nmask >> bitp) & 1;                             \
          if (cp && (d > mv || (d == mv && c < fmi))) { mv = d; fmi = c; } \
          const float dn = -d;                                             \
          if (cn && (dn > mv || (dn == mv && (c + 64) < fmi))) { mv = dn; fmi = c + 64; } \
        }                                                                  \
        _Pragma("unroll") for (int off = 16; off < 64; off <<= 1) {        \
          const float ov = __shfl_xor(mv, off);                            \
          const int oi = __shfl_xor(fmi, off);                             \
          if (ov > mv || (ov == mv && oi < fmi)) { mv = ov; fmi = oi; }    \
        }                                                                  \
        bi = fmi;                                                          \
      }                                                                    \
      if (g == 0) {                                                        \
        const int row_global = rowbase + grp * 16 + r16;                   \
        const int b = row_global >> 13, t = row_global & (SS - 1);         \
        bucket[((size_t)(b * HH + h)) * SS + t] = (unsigned char)bi;       \
      }                                                                    \
    }                                                                      \
  }

__global__ __launch_bounds__(256, 2) void hash_kernel(const float* __restrict__ qk,
                                                      const float* __restrict__ rotT,
                                                      const unsigned short* __restrict__ qhi,
                                                      const unsigned short* __restrict__ qlo,
                                                      const unsigned short* __restrict__ rhiT,
                                                      const unsigned short* __restrict__ rloT,
                                                      unsigned char* __restrict__ bucket) {
  const int tid = threadIdx.x;
  const int lane = tid & 63, w = tid >> 6;
  const int r16 = lane & 15, g = lane >> 4;
  const int rowbase = blockIdx.x * 128 + w * 32;  // this wave's 32 global rows
  const int h0 = blockIdx.z * 4;

  bf16x8 qh0[2], qh1[2], ql0[2], ql1[2];
#pragma unroll
  for (int grp = 0; grp < 2; ++grp) {
    const size_t qoff = (size_t)(rowbase + grp * 16 + r16) * DD;
    qh0[grp] = *(const bf16x8*)(qhi + qoff + g * 8);
    qh1[grp] = *(const bf16x8*)(qhi + qoff + 32 + g * 8);
    ql0[grp] = *(const bf16x8*)(qlo + qoff + g * 8);
    ql1[grp] = *(const bf16x8*)(qlo + qoff + 32 + g * 8);
  }

  bf16x8 Ah0[4], Ah1[4], Al0[4], Al1[4];
  bf16x8 Bh0[4], Bh1[4], Bl0[4], Bl1[4];

  LOAD_ROT(h0 + 0, Ah0, Ah1, Al0, Al1);
  LOAD_ROT(h0 + 1, Bh0, Bh1, Bl0, Bl1);
  COMPUTE_H(h0 + 0, Ah0, Ah1, Al0, Al1);
  LOAD_ROT(h0 + 2, Ah0, Ah1, Al0, Al1);
  COMPUTE_H(h0 + 1, Bh0, Bh1, Bl0, Bl1);
  LOAD_ROT(h0 + 3, Bh0, Bh1, Bl0, Bl1);
  COMPUTE_H(h0 + 2, Ah0, Ah1, Al0, Al1);
  COMPUTE_H(h0 + 3, Bh0, Bh1, Bl0, Bl1);
}

// ---------------------------------------------------------------------------
// Kernel 2: stable counting sort per (b,h), 1024 threads, shfl_up scan.
// ---------------------------------------------------------------------------
__global__ __launch_bounds__(1024) void sort_kernel(const unsigned char* __restrict__ bucket,
                                                    int* __restrict__ sticker) {
  __shared__ unsigned char lb[SS];
  __shared__ unsigned int hist[NB * NCHUNK];
  __shared__ unsigned int wtot[16];
  const int tid = threadIdx.x;
  const int bh = blockIdx.x;
  const int lane = tid & 63, wid = tid >> 6;

  if (tid < 512)
    ((uint4*)lb)[tid] = ((const uint4*)(bucket + (size_t)bh * SS))[tid];
#pragma unroll
  for (int k = 0; k < (NB * NCHUNK) / 1024; ++k) hist[tid + k * 1024] = 0u;
  __syncthreads();

#pragma unroll
  for (int rep = 0; rep < SS / 1024; ++rep) {
    const int t = rep * 1024 + tid;
    atomicAdd(&hist[(int)lb[t] * NCHUNK + (t >> 6)], 1u);
  }
  __syncthreads();

  unsigned int segsum = 0u;
  const int base = tid * 16;
#pragma unroll
  for (int e = 0; e < 16; ++e) segsum += hist[base + e];

  unsigned int val = segsum;
#pragma unroll
  for (int off = 1; off < 64; off <<= 1) {
    const unsigned int tmp = __shfl_up(val, off);
    if (lane >= off) val += tmp;
  }
  if (lane == 63) wtot[wid] = val;
  __syncthreads();
  if (wid == 0 && lane < 16) {
    unsigned int wv = wtot[lane];
#pragma unroll
    for (int off = 1; off < 16; off <<= 1) {
      const unsigned int t2 = __shfl_up(wv, off);
      if (lane >= off) wv += t2;
    }
    wtot[lane] = wv;
  }
  __syncthreads();
  const unsigned int woff = (wid == 0) ? 0u : wtot[wid - 1];
  unsigned int run = (val + woff) - segsum;
#pragma unroll
  for (int e = 0; e < 16; ++e) {
    const unsigned int tv = hist[base + e];
    hist[base + e] = run;
    run += tv;
  }
  __syncthreads();

#pragma unroll
  for (int rep = 0; rep < NCHUNK / 16; ++rep) {
    const int c = rep * 16 + wid;
    const int t = c * 64 + lane;
    const int bk = lb[t];
    unsigned long long mm = ~0ull;
#pragma unroll
    for (int bit = 0; bit < 7; ++bit) {
      const unsigned long long bal = __ballot((bk >> bit) & 1);
      mm &= ((bk >> bit) & 1) ? bal : ~bal;
    }
    const int rank = __popcll(mm & ((1ull << lane) - 1ull));
    const int pos = (int)hist[bk * NCHUNK + c] + rank;
    sticker[(size_t)bh * SS + pos] = t;
  }
}

// ---------------------------------------------------------------------------
// Kernel 3: fused attention. V transpose staged at u32 granularity over ALL
// 128 key rows: vt32[d][j] holds rows (2j,2j+1) at column d. Thread
// (r = row-pair [0,64), s = d-seg of 16): 4 uint4 loads, 16 ds_write_b32
// (vs 32 ds_write_u16 before). Fragment contents byte-identical.
// ---------------------------------------------------------------------------
__global__ __launch_bounds__(256) void attn_kernel(const unsigned short* __restrict__ qhat,
                                                   const unsigned short* __restrict__ vb,
                                                   const float* __restrict__ snorm,
                                                   const int* __restrict__ sticker,
                                                   unsigned short* __restrict__ so,
                                                   float* __restrict__ slogits,
                                                   const int b_base) {
  __shared__ __align__(16) unsigned short kbps[128 * 72];   // aliased: kb -> ps -> ob
  __shared__ __align__(16) unsigned int vt32[64][68];       // [d][row-pair], 128 rows packed
  __shared__ int st[128];
  __shared__ float sn_s[64];
  const int tid = threadIdx.x;
  const int bin = blockIdx.y, bl = blockIdx.x, h = blockIdx.z;
  const int b = b_base + bl;
  const int bh = b * HH + h;
  const int prev = (h * NB + bin + CHUNKS - 1) & (CHUNKS - 1);
  const int ph = prev >> 7, pbin = prev & 127;

  if (tid < 128) {
    const int j = tid;
    const int src = (j < 64) ? (bh * SS + bin * 64 + j)
                             : ((b * HH + ph) * SS + pbin * 64 + (j - 64));
    st[j] = sticker[src];
  }
  __syncthreads();

  // kb staging: 128 rows x 2 halves (b128 writes)
  {
    const int row = tid >> 1, half = tid & 1;
    const int trow = st[row];
    const uint4* qsrc = (const uint4*)(qhat + ((size_t)b * SS + trow) * DD) + half * 4;
    uint4 q0 = qsrc[0], q1 = qsrc[1], q2 = qsrc[2], q3 = qsrc[3];
    unsigned short* kd = &kbps[row * 72 + half * 32];
    *(uint4*)&kd[0] = q0;
    *(uint4*)&kd[8] = q1;
    *(uint4*)&kd[16] = q2;
    *(uint4*)&kd[24] = q3;
  }
  // vt staging: thread (r = row pair [0,64), s = d-seg of 16): rows 2r,2r+1,
  // d in [s*16, s*16+16): 4 uint4 loads -> 16 ds_write_b32.
  {
    const int r = tid >> 2, s = tid & 3;
    const int trA = st[2 * r], trB = st[2 * r + 1];
    const uint4* pa4 = (const uint4*)(vb + ((size_t)b * SS + trA) * DD + s * 16);
    const uint4* pb4 = (const uint4*)(vb + ((size_t)b * SS + trB) * DD + s * 16);
    uint4 a0 = pa4[0], a1 = pa4[1];
    uint4 b0 = pb4[0], b1 = pb4[1];
    const unsigned int av[8] = {a0.x, a0.y, a0.z, a0.w, a1.x, a1.y, a1.z, a1.w};
    const unsigned int bw[8] = {b0.x, b0.y, b0.z, b0.w, b1.x, b1.y, b1.z, b1.w};
#pragma unroll
    for (int k = 0; k < 8; ++k) {
      const int d = s * 16 + 2 * k;
      vt32[d][r]     = (av[k] & 0xffffu) | (bw[k] << 16);
      vt32[d + 1][r] = (av[k] >> 16) | (bw[k] & 0xffff0000u);
    }
  }
  if (tid < 64) sn_s[tid] = snorm[(size_t)b * SS + st[tid]];
  __syncthreads();

  const int lane = tid & 63, w = tid >> 6;
  const int r16 = lane & 15, g = lane >> 4;

  f32x4 acc[8];
#pragma unroll
  for (int n = 0; n < 8; ++n) acc[n] = (f32x4){0.f, 0.f, 0.f, 0.f};
  bf16x8 af0 = *(const bf16x8*)&kbps[(16 * w + r16) * 72 + g * 8];
  bf16x8 af1 = *(const bf16x8*)&kbps[(16 * w + r16) * 72 + 32 + g * 8];
#pragma unroll
  for (int n = 0; n < 8; ++n) {
    bf16x8 bf0 = *(const bf16x8*)&kbps[(16 * n + r16) * 72 + g * 8];
    bf16x8 bf1 = *(const bf16x8*)&kbps[(16 * n + r16) * 72 + 32 + g * 8];
    acc[n] = __builtin_amdgcn_mfma_f32_16x16x32_bf16(af0, bf0, acc[n], 0, 0, 0);
    acc[n] = __builtin_amdgcn_mfma_f32_16x16x32_bf16(af1, bf1, acc[n], 0, 0, 0);
  }

  int tkj[8];
#pragma unroll
  for (int n = 0; n < 8; ++n) tkj[n] = st[16 * n + r16];

  float lse4[4];
#pragma unroll
  for (int i = 0; i < 4; ++i) {
    const int q = 16 * w + 4 * g + i;
    const int tq = st[q];
    const float sq = sn_s[q] * 0.125f;
    float mm = -3.4e38f;
#pragma unroll
    for (int n = 0; n < 8; ++n) {
      float s = acc[n][i] * sq;
      s = (tkj[n] > tq) ? -1e38f : ((tkj[n] == tq) ? -50000.f : s);
      acc[n][i] = s;
      mm = fmaxf(mm, s);
    }
    mm = fmaxf(mm, __shfl_xor(mm, 1));
    mm = fmaxf(mm, __shfl_xor(mm, 2));
    mm = fmaxf(mm, __shfl_xor(mm, 4));
    mm = fmaxf(mm, __shfl_xor(mm, 8));
    float sum = 0.f;
#pragma unroll
    for (int n = 0; n < 8; ++n) {
      const float e = __expf(acc[n][i] - mm);
      acc[n][i] = e;
      sum += e;
    }
    sum += __shfl_xor(sum, 1);
    sum += __shfl_xor(sum, 2);
    sum += __shfl_xor(sum, 4);
    sum += __shfl_xor(sum, 8);
    lse4[i] = mm + logf(sum);
    const float rinv = __builtin_amdgcn_rcpf(sum);
#pragma unroll
    for (int n = 0; n < 8; ++n) acc[n][i] *= rinv;
  }

  __syncthreads();  // kb reads done -> overwrite with ps

#pragma unroll
  for (int i = 0; i < 4; ++i) {
    const int q = 16 * w + 4 * g + i;
    const int qx = ((q >> 2) & 3) << 3;   // XOR swizzle (u16 units)
#pragma unroll
    for (int n = 0; n < 8; ++n)
      kbps[q * 136 + ((16 * n + r16) ^ qx)] = f2b(acc[n][i]);
  }
  if (r16 == 0) {
#pragma unroll
    for (int i = 0; i < 4; ++i) {
      const int q = 16 * w + 4 * g + i;
      slogits[((size_t)b * SS + st[q]) * HH + h] = lse4[i];
    }
  }
  __syncthreads();

  f32x4 o[4];
#pragma unroll
  for (int n = 0; n < 4; ++n) o[n] = (f32x4){0.f, 0.f, 0.f, 0.f};
  const int pqx = (((16 * w + r16) >> 2) & 3) << 3;
#pragma unroll
  for (int kk = 0; kk < 4; ++kk) {
    bf16x8 pa = *(const bf16x8*)&kbps[(16 * w + r16) * 136 + ((kk * 32 + g * 8) ^ pqx)];
#pragma unroll
    for (int n = 0; n < 4; ++n) {
      // rows kk*32+g*8 .. +7 at column d = 16n+r16 : 4 u32 = bf16x8
      bf16x8 vbf = *(const bf16x8*)&vt32[16 * n + r16][kk * 16 + g * 4];
      o[n] = __builtin_amdgcn_mfma_f32_16x16x32_bf16(pa, vbf, o[n], 0, 0, 0);
    }
  }

  __syncthreads();  // ps reads done -> overwrite with ob
#pragma unroll
  for (int i = 0; i < 4; ++i) {
    const int q = 16 * w + 4 * g + i;
    const int qx = ((q >> 2) & 3) << 3;
#pragma unroll
    for (int n = 0; n < 4; ++n)
      kbps[q * 72 + ((16 * n + r16) ^ qx)] = f2b(o[n][i]);
  }
  __syncthreads();

  {
    const int row = tid >> 2, q4 = tid & 3;
    const int rx = ((row >> 2) & 3) << 3;
    uint4 x0 = *(uint4*)&kbps[row * 72 + ((q4 * 16) ^ rx)];
    uint4 x1 = *(uint4*)&kbps[row * 72 + ((q4 * 16 + 8) ^ rx)];
    unsigned short* dst = so + (((size_t)bl * SS + st[row]) * HH + h) * DD + q4 * 16;
    *(uint4*)&dst[0] = x0;
    *(uint4*)&dst[8] = x1;
  }
}

// ---------------------------------------------------------------------------
// Kernel 4: combine — out[b,t] = sum_h w_h * o_h[b,t,h], w_h = exp(l_h-m)/sum.
// ---------------------------------------------------------------------------
__global__ __launch_bounds__(256) void gather_out_kernel(const unsigned short* __restrict__ so,
                                                         const float* __restrict__ slogits,
                                                         float* __restrict__ out,
                                                         const int b_base) {
  const int idx = blockIdx.x * 256 + threadIdx.x;
  const int seg = idx & 7;
  const int btl = idx >> 3;

  const float* lrow = slogits + ((size_t)b_base * SS + btl) * HH;
  float4 l0 = ((const float4*)lrow)[0];
  float4 l1 = ((const float4*)lrow)[1];
  float l[8] = {l0.x, l0.y, l0.z, l0.w, l1.x, l1.y, l1.z, l1.w};
  float m = -3.4e38f;
#pragma unroll
  for (int h = 0; h < HH; ++h) m = fmaxf(m, l[h]);
  float ex[8];
  float sum = 0.f;
#pragma unroll
  for (int h = 0; h < HH; ++h) {
    ex[h] = __expf(l[h] - m);
    sum += ex[h];
  }
  const float rinv = __builtin_amdgcn_rcpf(sum);

  float acc[8];
#pragma unroll
  for (int k = 0; k < 8; ++k) acc[k] = 0.f;
#pragma unroll
  for (int h = 0; h < HH; ++h) {
    const float wgt = ex[h] * rinv;
    uint4 u = *(const uint4*)(so + ((size_t)btl * HH + h) * DD + seg * 8);
    const unsigned int uu[4] = {u.x, u.y, u.z, u.w};
#pragma unroll
    for (int k = 0; k < 4; ++k) {
      acc[2 * k] += wgt * b2f((unsigned short)(uu[k] & 0xffffu));
      acc[2 * k + 1] += wgt * b2f((unsigned short)(uu[k] >> 16));
    }
  }
  float* dst = out + ((size_t)b_base * SS + btl) * DD + seg * 8;
  float4 o0, o1;
  o0.x = acc[0]; o0.y = acc[1]; o0.z = acc[2]; o0.w = acc[3];
  o1.x = acc[4]; o1.y = acc[5]; o1.z = acc[6]; o1.w = acc[7];
  ((float4*)dst)[0] = o0;
  ((float4*)dst)[1] = o1;
}

// ---------------------------------------------------------------------------
extern "C" void kernel_launch(void* const* d_in, const int* in_sizes, int n_in,
                              void* d_out, int out_size, void* d_ws, size_t ws_size,
                              hipStream_t stream) {
  (void)in_sizes; (void)n_in; (void)out_size;
  const float* qk = (const float*)d_in[0];
  const float* v = (const float*)d_in[1];
  const float* rot = (const float*)d_in[2];
  float* out = (float*)d_out;

  char* ws = (char*)d_ws;
  int* sticker = (int*)ws;                                              // @0,          2 MB
  float* slogits = (float*)(ws + ((size_t)2 << 20));                    // @2M,         2 MB
  float* snorm = (float*)(ws + ((size_t)4 << 20));                      // @4M,       256 KB
  unsigned char* bucket = (unsigned char*)(ws + ((size_t)4 << 20) + ((size_t)256 << 10));  // 512 KB
  float* rotT = (float*)(ws + ((size_t)4 << 20) + ((size_t)768 << 10)); // @4M+768K,  128 KB
  unsigned short* rhiT = (unsigned short*)(ws + ((size_t)4 << 20) + ((size_t)896 << 10));  // 64 KB
  unsigned short* rloT = (unsigned short*)(ws + ((size_t)4 << 20) + ((size_t)960 << 10));  // 64 KB
  unsigned short* qhat = (unsigned short*)(ws + ((size_t)5 << 20));     // @5M,         8 MB
  unsigned short* vb = (unsigned short*)(ws + ((size_t)13 << 20));      // @13M,        8 MB
  unsigned short* qhi = (unsigned short*)(ws + ((size_t)21 << 20));     // @21M,        8 MB
  unsigned short* qlo = (unsigned short*)(ws + ((size_t)29 << 20));     // @29M,        8 MB
  unsigned short* so = (unsigned short*)(ws + ((size_t)37 << 20));      // @37M, 32 or 64 MB

  rott_kernel<<<8, 256, 0, stream>>>(rot, rotT, rhiT, rloT);
  prep_kernel<<<(BB * SS * 8) / 256, 256, 0, stream>>>(qk, v, qhat, vb, qhi, qlo, snorm);
  hash_kernel<<<dim3(512, 1, 2), 256, 0, stream>>>(qk, rotT, qhi, qlo, rhiT, rloT, bucket);
  sort_kernel<<<BB * HH, 1024, 0, stream>>>(bucket, sticker);

  const size_t need_full = ((size_t)37 << 20) + (size_t)BB * SS * HH * DD * 2;
  if (ws_size >= need_full) {
    attn_kernel<<<dim3(BB, NB, HH), 256, 0, stream>>>(qhat, vb, snorm, sticker, so, slogits, 0);
    gather_out_kernel<<<(BB * SS * 8) / 256, 256, 0, stream>>>(so, slogits, out, 0);
  } else {
    for (int half = 0; half < 2; ++half) {
      const int b_base = half * (BB / 2);
      attn_kernel<<<dim3(BB / 2, NB, HH), 256, 0, stream>>>(qhat, vb, snorm, sticker, so, slogits, b_base);
      gather_out_kernel<<<(BB / 2 * SS * 8) / 256, 256, 0, stream>>>(so, slogits, out, b_base);
    }
  }
}

// Round 27
// 150.836 us; speedup vs baseline: 1.0080x; 1.0080x over previous
//
#include <hip/hip_runtime.h>
#include <hip/hip_bf16.h>
#include <cstdint>
#include <cstddef>

#define BB 8
#define SS 8192
#define DD 64
#define HH 8
#define NB 128
#define NCHUNK 128   /* S / 64 */
#define CHUNKS 1024  /* H * NB */

typedef __attribute__((ext_vector_type(8))) short bf16x8;
typedef __attribute__((ext_vector_type(4))) float f32x4;

__device__ __forceinline__ unsigned short f2b(float x) {
  __hip_bfloat16 hb = __float2bfloat16(x);
  union { __hip_bfloat16 h; unsigned short u; } c; c.h = hb;
  return c.u;
}
__device__ __forceinline__ float b2f(unsigned short h) {
  union { unsigned int u; float f; } c; c.u = ((unsigned int)h) << 16;
  return c.f;
}

// ---------------------------------------------------------------------------
// Kernel 0: prep — qhat (normalized bf16), snorm (f32), vb (bf16), and the
// hi/lo bf16 split of raw qk (qhi/qlo) for the hash MFMA screen.
// ---------------------------------------------------------------------------
__global__ __launch_bounds__(256) void prep_kernel(const float* __restrict__ qk,
                                                   const float* __restrict__ v,
                                                   unsigned short* __restrict__ qhat,
                                                   unsigned short* __restrict__ vb,
                                                   unsigned short* __restrict__ qhi,
                                                   unsigned short* __restrict__ qlo,
                                                   float* __restrict__ snorm) {
  const int idx = blockIdx.x * 256 + threadIdx.x;
  const int row = idx >> 3, seg = idx & 7;
  const size_t base = (size_t)row * DD + seg * 8;

  float4 a0 = ((const float4*)(qk + base))[0];
  float4 a1 = ((const float4*)(qk + base))[1];
  float vals[8] = {a0.x, a0.y, a0.z, a0.w, a1.x, a1.y, a1.z, a1.w};
  float ssq = 0.f;
#pragma unroll
  for (int k = 0; k < 8; ++k) ssq += vals[k] * vals[k];
  ssq += __shfl_xor(ssq, 1);
  ssq += __shfl_xor(ssq, 2);
  ssq += __shfl_xor(ssq, 4);
  const float r = rsqrtf(ssq + 1e-6f);
  const float sn = (ssq + 1e-6f) * r;  // sqrt(ssq + eps)
  uint4 qo;
  unsigned int* qp = (unsigned int*)&qo;
#pragma unroll
  for (int k = 0; k < 4; ++k)
    qp[k] = (unsigned int)f2b(vals[2 * k] * r) | ((unsigned int)f2b(vals[2 * k + 1] * r) << 16);
  *(uint4*)(qhat + base) = qo;
  if (seg == 0) snorm[row] = sn;

  uint4 ho, lo4;
  unsigned int* hp = (unsigned int*)&ho;
  unsigned int* lp = (unsigned int*)&lo4;
#pragma unroll
  for (int k = 0; k < 4; ++k) {
    const unsigned short h0 = f2b(vals[2 * k]);
    const unsigned short h1 = f2b(vals[2 * k + 1]);
    const unsigned short l0 = f2b(vals[2 * k] - b2f(h0));
    const unsigned short l1 = f2b(vals[2 * k + 1] - b2f(h1));
    hp[k] = (unsigned int)h0 | ((unsigned int)h1 << 16);
    lp[k] = (unsigned int)l0 | ((unsigned int)l1 << 16);
  }
  *(uint4*)(qhi + base) = ho;
  *(uint4*)(qlo + base) = lo4;

  float4 v0 = ((const float4*)(v + base))[0];
  float4 v1 = ((const float4*)(v + base))[1];
  float vv[8] = {v0.x, v0.y, v0.z, v0.w, v1.x, v1.y, v1.z, v1.w};
  uint4 vo;
  unsigned int* vp = (unsigned int*)&vo;
#pragma unroll
  for (int k = 0; k < 4; ++k)
    vp[k] = (unsigned int)f2b(vv[2 * k]) | ((unsigned int)f2b(vv[2 * k + 1]) << 16);
  *(uint4*)(vb + base) = vo;
}

// ---------------------------------------------------------------------------
// Kernel 0b: transpose rot -> rotT (f32 [512][64]) + hi/lo bf16 split
// rhiT/rloT ([512][64]). Grid 8 x 256, one 64x64 tile per block.
// ---------------------------------------------------------------------------
__global__ __launch_bounds__(256) void rott_kernel(const float* __restrict__ rot,
                                                   float* __restrict__ rotT,
                                                   unsigned short* __restrict__ rhiT,
                                                   unsigned short* __restrict__ rloT) {
  __shared__ float tile[64][68];
  const int tid = threadIdx.x;
  const int hi0 = blockIdx.x * 64;
#pragma unroll
  for (int rep = 0; rep < 4; ++rep) {
    const int j = rep * 256 + tid;
    const int f = j >> 4, c4 = (j & 15) * 4;
    const float4 vv = *(const float4*)(rot + (size_t)f * (HH * 64) + hi0 + c4);
    *(float4*)&tile[f][c4] = vv;
  }
  __syncthreads();
#pragma unroll
  for (int rep = 0; rep < 4; ++rep) {
    const int j = rep * 256 + tid;
    const int c = j >> 4, f4 = (j & 15) * 4;
    float4 o;
    o.x = tile[f4 + 0][c];
    o.y = tile[f4 + 1][c];
    o.z = tile[f4 + 2][c];
    o.w = tile[f4 + 3][c];
    *(float4*)(rotT + (size_t)(hi0 + c) * 64 + f4) = o;
    const float xs[4] = {o.x, o.y, o.z, o.w};
    unsigned int hpack[2], lpack[2];
#pragma unroll
    for (int e = 0; e < 2; ++e) {
      const unsigned short h0 = f2b(xs[2 * e]);
      const unsigned short h1 = f2b(xs[2 * e + 1]);
      const unsigned short l0 = f2b(xs[2 * e] - b2f(h0));
      const unsigned short l1 = f2b(xs[2 * e + 1] - b2f(h1));
      hpack[e] = (unsigned int)h0 | ((unsigned int)h1 << 16);
      lpack[e] = (unsigned int)l0 | ((unsigned int)l1 << 16);
    }
    uint2 hv; hv.x = hpack[0]; hv.y = hpack[1];
    uint2 lv; lv.x = lpack[0]; lv.y = lpack[1];
    *(uint2*)&rhiT[(size_t)(hi0 + c) * 64 + f4] = hv;
    *(uint2*)&rloT[(size_t)(hi0 + c) * 64 + f4] = lv;
  }
}

// ---------------------------------------------------------------------------
// Kernel 1: LSH hash — transposed MFMA screen with manual cross-h double
// buffering. Exact-f32 fallback (bit-identical serial chain) when >=2
// candidates within TH of the max. Grid (512, 1, 2).
// ---------------------------------------------------------------------------
#define TH 0.015625f

#define LOAD_ROT(HV, RH0, RH1, RL0, RL1)                                   \
  {                                                                        \
    _Pragma("unroll") for (int n = 0; n < 4; ++n) {                        \
      const size_t roff = (size_t)((HV) * 64 + 16 * n + r16) * DD;         \
      RH0[n] = *(const bf16x8*)(rhiT + roff + g * 8);                      \
      RH1[n] = *(const bf16x8*)(rhiT + roff + 32 + g * 8);                 \
      RL0[n] = *(const bf16x8*)(rloT + roff + g * 8);                      \
      RL1[n] = *(const bf16x8*)(rloT + roff + 32 + g * 8);                 \
    }                                                                      \
  }

#define COMPUTE_H(HV, RH0, RH1, RL0, RL1)                                  \
  {                                                                        \
    const int h = (HV);                                                    \
    f32x4 acc[2][4];                                                       \
    _Pragma("unroll") for (int grp = 0; grp < 2; ++grp)                    \
      _Pragma("unroll") for (int n = 0; n < 4; ++n)                        \
        acc[grp][n] = (f32x4){0.f, 0.f, 0.f, 0.f};                         \
    _Pragma("unroll") for (int n = 0; n < 4; ++n) {                        \
      _Pragma("unroll") for (int grp = 0; grp < 2; ++grp) {                \
        acc[grp][n] = __builtin_amdgcn_mfma_f32_16x16x32_bf16(RH0[n], qh0[grp], acc[grp][n], 0, 0, 0); \
        acc[grp][n] = __builtin_amdgcn_mfma_f32_16x16x32_bf16(RL0[n], qh0[grp], acc[grp][n], 0, 0, 0); \
        acc[grp][n] = __builtin_amdgcn_mfma_f32_16x16x32_bf16(RH0[n], ql0[grp], acc[grp][n], 0, 0, 0); \
        acc[grp][n] = __builtin_amdgcn_mfma_f32_16x16x32_bf16(RH1[n], qh1[grp], acc[grp][n], 0, 0, 0); \
        acc[grp][n] = __builtin_amdgcn_mfma_f32_16x16x32_bf16(RL1[n], qh1[grp], acc[grp][n], 0, 0, 0); \
        acc[grp][n] = __builtin_amdgcn_mfma_f32_16x16x32_bf16(RH1[n], ql1[grp], acc[grp][n], 0, 0, 0); \
      }                                                                    \
    }                                                                      \
    _Pragma("unroll") for (int grp = 0; grp < 2; ++grp) {                  \
      float bv = 0.f;                                                      \
      _Pragma("unroll") for (int n = 0; n < 4; ++n)                        \
        _Pragma("unroll") for (int i = 0; i < 4; ++i)                      \
          bv = fmaxf(bv, fabsf(acc[grp][n][i]));                           \
      bv = fmaxf(bv, __shfl_xor(bv, 16));                                  \
      bv = fmaxf(bv, __shfl_xor(bv, 32));                                  \
      int mi = 9999;                                                       \
      _Pragma("unroll") for (int n = 0; n < 4; ++n)                        \
        _Pragma("unroll") for (int i = 0; i < 4; ++i) {                    \
          const float vv = acc[grp][n][i];                                 \
          const int c = 16 * n + 4 * g + i;                                \
          const int idx = (vv < 0.f) ? (c + 64) : c;                       \
          if (fabsf(vv) == bv && idx < mi) mi = idx;                       \
        }                                                                  \
      {                                                                    \
        const int o1 = __shfl_xor(mi, 16); mi = (o1 < mi) ? o1 : mi;       \
        const int o2 = __shfl_xor(mi, 32); mi = (o2 < mi) ? o2 : mi;       \
      }                                                                    \
      unsigned int pmask = 0, nmask = 0;                                   \
      _Pragma("unroll") for (int n = 0; n < 4; ++n)                        \
        _Pragma("unroll") for (int i = 0; i < 4; ++i) {                    \
          if (acc[grp][n][i] >= bv - TH) pmask |= 1u << (n * 4 + i);       \
          if (-acc[grp][n][i] >= bv - TH) nmask |= 1u << (n * 4 + i);      \
        }                                                                  \
      int cnt = __popc(pmask) + __popc(nmask);                             \
      cnt += __shfl_xor(cnt, 16);                                          \
      cnt += __shfl_xor(cnt, 32);                                          \
      int bi = mi;                                                         \
      if (cnt >= 2) {                                                      \
        const float* qrowp = qk + (size_t)(rowbase + grp * 16 + r16) * DD; \
        float mv = -3.4e38f;                                               \
        int fmi = 9999;                                                    \
        unsigned int am = pmask | nmask;                                   \
        while (am) {                                                       \
          const int bitp = __ffs(am) - 1;                                  \
          am &= am - 1;                                                    \
          const int n = bitp >> 2, i = bitp & 3;                           \
          const int c = 16 * n + 4 * g + i;                                \
          const float* rrow = rotT + (size_t)(h * 64 + c) * DD;            \
          float d = 0.f;                                                   \
          _Pragma("unroll") for (int f4 = 0; f4 < 16; ++f4) {              \
            const float4 qv = *(const float4*)(qrowp + 4 * f4);            \
            const float4 rv = *(const float4*)(rrow + 4 * f4);             \
            d = fmaf(qv.x, rv.x, d);                                       \
            d = fmaf(qv.y, rv.y, d);                                       \
            d = fmaf(qv.z, rv.z, d);                                       \
            d = fmaf(qv.w, rv.w, d);                                       \
          }                                                                \
          const bool cp = (pmask >> bitp) & 1;                             \
          const bool cn = (nmask >> bitp) & 1;                             \
          if (cp && (d > mv || (d == mv && c < fmi))) { mv = d; fmi = c; } \
          const float dn = -d;                                             \
          if (cn && (dn > mv || (dn == mv && (c + 64) < fmi))) { mv = dn; fmi = c + 64; } \
        }                                                                  \
        _Pragma("unroll") for (int off = 16; off < 64; off <<= 1) {        \
          const float ov = __shfl_xor(mv, off);                            \
          const int oi = __shfl_xor(fmi, off);                             \
          if (ov > mv || (ov == mv && oi < fmi)) { mv = ov; fmi = oi; }    \
        }                                                                  \
        bi = fmi;                                                          \
      }                                                                    \
      if (g == 0) {                                                        \
        const int row_global = rowbase + grp * 16 + r16;                   \
        const int b = row_global >> 13, t = row_global & (SS - 1);         \
        bucket[((size_t)(b * HH + h)) * SS + t] = (unsigned char)bi;       \
      }                                                                    \
    }                                                                      \
  }

__global__ __launch_bounds__(256, 2) void hash_kernel(const float* __restrict__ qk,
                                                      const float* __restrict__ rotT,
                                                      const unsigned short* __restrict__ qhi,
                                                      const unsigned short* __restrict__ qlo,
                                                      const unsigned short* __restrict__ rhiT,
                                                      const unsigned short* __restrict__ rloT,
                                                      unsigned char* __restrict__ bucket) {
  const int tid = threadIdx.x;
  const int lane = tid & 63, w = tid >> 6;
  const int r16 = lane & 15, g = lane >> 4;
  const int rowbase = blockIdx.x * 128 + w * 32;  // this wave's 32 global rows
  const int h0 = blockIdx.z * 4;

  bf16x8 qh0[2], qh1[2], ql0[2], ql1[2];
#pragma unroll
  for (int grp = 0; grp < 2; ++grp) {
    const size_t qoff = (size_t)(rowbase + grp * 16 + r16) * DD;
    qh0[grp] = *(const bf16x8*)(qhi + qoff + g * 8);
    qh1[grp] = *(const bf16x8*)(qhi + qoff + 32 + g * 8);
    ql0[grp] = *(const bf16x8*)(qlo + qoff + g * 8);
    ql1[grp] = *(const bf16x8*)(qlo + qoff + 32 + g * 8);
  }

  bf16x8 Ah0[4], Ah1[4], Al0[4], Al1[4];
  bf16x8 Bh0[4], Bh1[4], Bl0[4], Bl1[4];

  LOAD_ROT(h0 + 0, Ah0, Ah1, Al0, Al1);
  LOAD_ROT(h0 + 1, Bh0, Bh1, Bl0, Bl1);
  COMPUTE_H(h0 + 0, Ah0, Ah1, Al0, Al1);
  LOAD_ROT(h0 + 2, Ah0, Ah1, Al0, Al1);
  COMPUTE_H(h0 + 1, Bh0, Bh1, Bl0, Bl1);
  LOAD_ROT(h0 + 3, Bh0, Bh1, Bl0, Bl1);
  COMPUTE_H(h0 + 2, Ah0, Ah1, Al0, Al1);
  COMPUTE_H(h0 + 3, Bh0, Bh1, Bl0, Bl1);
}

// ---------------------------------------------------------------------------
// Kernel 2: stable counting sort per (b,h), 1024 threads, shfl_up scan.
// ---------------------------------------------------------------------------
__global__ __launch_bounds__(1024) void sort_kernel(const unsigned char* __restrict__ bucket,
                                                    int* __restrict__ sticker) {
  __shared__ unsigned char lb[SS];
  __shared__ unsigned int hist[NB * NCHUNK];
  __shared__ unsigned int wtot[16];
  const int tid = threadIdx.x;
  const int bh = blockIdx.x;
  const int lane = tid & 63, wid = tid >> 6;

  if (tid < 512)
    ((uint4*)lb)[tid] = ((const uint4*)(bucket + (size_t)bh * SS))[tid];
#pragma unroll
  for (int k = 0; k < (NB * NCHUNK) / 1024; ++k) hist[tid + k * 1024] = 0u;
  __syncthreads();

#pragma unroll
  for (int rep = 0; rep < SS / 1024; ++rep) {
    const int t = rep * 1024 + tid;
    atomicAdd(&hist[(int)lb[t] * NCHUNK + (t >> 6)], 1u);
  }
  __syncthreads();

  unsigned int segsum = 0u;
  const int base = tid * 16;
#pragma unroll
  for (int e = 0; e < 16; ++e) segsum += hist[base + e];

  unsigned int val = segsum;
#pragma unroll
  for (int off = 1; off < 64; off <<= 1) {
    const unsigned int tmp = __shfl_up(val, off);
    if (lane >= off) val += tmp;
  }
  if (lane == 63) wtot[wid] = val;
  __syncthreads();
  if (wid == 0 && lane < 16) {
    unsigned int wv = wtot[lane];
#pragma unroll
    for (int off = 1; off < 16; off <<= 1) {
      const unsigned int t2 = __shfl_up(wv, off);
      if (lane >= off) wv += t2;
    }
    wtot[lane] = wv;
  }
  __syncthreads();
  const unsigned int woff = (wid == 0) ? 0u : wtot[wid - 1];
  unsigned int run = (val + woff) - segsum;
#pragma unroll
  for (int e = 0; e < 16; ++e) {
    const unsigned int tv = hist[base + e];
    hist[base + e] = run;
    run += tv;
  }
  __syncthreads();

#pragma unroll
  for (int rep = 0; rep < NCHUNK / 16; ++rep) {
    const int c = rep * 16 + wid;
    const int t = c * 64 + lane;
    const int bk = lb[t];
    unsigned long long mm = ~0ull;
#pragma unroll
    for (int bit = 0; bit < 7; ++bit) {
      const unsigned long long bal = __ballot((bk >> bit) & 1);
      mm &= ((bk >> bit) & 1) ? bal : ~bal;
    }
    const int rank = __popcll(mm & ((1ull << lane) - 1ull));
    const int pos = (int)hist[bk * NCHUNK + c] + rank;
    sticker[(size_t)bh * SS + pos] = t;
  }
}

// ---------------------------------------------------------------------------
// Kernel 3: fused attention. p computed as exp(s-mm)*rcp(sum) — the exp
// values from the lse-sum are reused (32 fewer __expf per thread).
// ---------------------------------------------------------------------------
__global__ __launch_bounds__(256) void attn_kernel(const unsigned short* __restrict__ qhat,
                                                   const unsigned short* __restrict__ vb,
                                                   const float* __restrict__ snorm,
                                                   const int* __restrict__ sticker,
                                                   unsigned short* __restrict__ so,
                                                   float* __restrict__ slogits,
                                                   const int b_base) {
  __shared__ __align__(16) unsigned short kbps[128 * 72];   // aliased: kb -> ps -> ob
  __shared__ __align__(16) unsigned short vt[64][136];
  __shared__ int st[128];
  __shared__ float sn_s[64];
  const int tid = threadIdx.x;
  const int bin = blockIdx.y, bl = blockIdx.x, h = blockIdx.z;
  const int b = b_base + bl;
  const int bh = b * HH + h;
  const int prev = (h * NB + bin + CHUNKS - 1) & (CHUNKS - 1);
  const int ph = prev >> 7, pbin = prev & 127;

  if (tid < 128) {
    const int j = tid;
    const int src = (j < 64) ? (bh * SS + bin * 64 + j)
                             : ((b * HH + ph) * SS + pbin * 64 + (j - 64));
    st[j] = sticker[src];
  }
  __syncthreads();

  {
    const int row = tid >> 1, half = tid & 1;
    const int trow = st[row];
    {
      const uint4* qsrc = (const uint4*)(qhat + ((size_t)b * SS + trow) * DD) + half * 4;
      uint4 q0 = qsrc[0], q1 = qsrc[1], q2 = qsrc[2], q3 = qsrc[3];
      unsigned short* kd = &kbps[row * 72 + half * 32];
      *(uint4*)&kd[0] = q0;
      *(uint4*)&kd[8] = q1;
      *(uint4*)&kd[16] = q2;
      *(uint4*)&kd[24] = q3;
    }
    {
      const uint4* vsrc = (const uint4*)(vb + ((size_t)b * SS + trow) * DD) + half * 4;
      uint4 w0 = vsrc[0], w1 = vsrc[1], w2 = vsrc[2], w3 = vsrc[3];
      unsigned int uu[16] = {w0.x, w0.y, w0.z, w0.w, w1.x, w1.y, w1.z, w1.w,
                             w2.x, w2.y, w2.z, w2.w, w3.x, w3.y, w3.z, w3.w};
#pragma unroll
      for (int m = 0; m < 16; ++m) {
        vt[half * 32 + 2 * m][row] = (unsigned short)(uu[m] & 0xffffu);
        vt[half * 32 + 2 * m + 1][row] = (unsigned short)(uu[m] >> 16);
      }
    }
  }
  if (tid < 64) sn_s[tid] = snorm[(size_t)b * SS + st[tid]];
  __syncthreads();

  const int lane = tid & 63, w = tid >> 6;
  const int r16 = lane & 15, g = lane >> 4;

  f32x4 acc[8];
#pragma unroll
  for (int n = 0; n < 8; ++n) acc[n] = (f32x4){0.f, 0.f, 0.f, 0.f};
  bf16x8 af0 = *(const bf16x8*)&kbps[(16 * w + r16) * 72 + g * 8];
  bf16x8 af1 = *(const bf16x8*)&kbps[(16 * w + r16) * 72 + 32 + g * 8];
#pragma unroll
  for (int n = 0; n < 8; ++n) {
    bf16x8 bf0 = *(const bf16x8*)&kbps[(16 * n + r16) * 72 + g * 8];
    bf16x8 bf1 = *(const bf16x8*)&kbps[(16 * n + r16) * 72 + 32 + g * 8];
    acc[n] = __builtin_amdgcn_mfma_f32_16x16x32_bf16(af0, bf0, acc[n], 0, 0, 0);
    acc[n] = __builtin_amdgcn_mfma_f32_16x16x32_bf16(af1, bf1, acc[n], 0, 0, 0);
  }

  int tkj[8];
#pragma unroll
  for (int n = 0; n < 8; ++n) tkj[n] = st[16 * n + r16];

  float lse4[4];
#pragma unroll
  for (int i = 0; i < 4; ++i) {
    const int q = 16 * w + 4 * g + i;
    const int tq = st[q];
    const float sq = sn_s[q] * 0.125f;
    float mm = -3.4e38f;
#pragma unroll
    for (int n = 0; n < 8; ++n) {
      float s = acc[n][i] * sq;
      s = (tkj[n] > tq) ? -1e38f : ((tkj[n] == tq) ? -50000.f : s);
      acc[n][i] = s;
      mm = fmaxf(mm, s);
    }
    mm = fmaxf(mm, __shfl_xor(mm, 1));
    mm = fmaxf(mm, __shfl_xor(mm, 2));
    mm = fmaxf(mm, __shfl_xor(mm, 4));
    mm = fmaxf(mm, __shfl_xor(mm, 8));
    float sum = 0.f;
#pragma unroll
    for (int n = 0; n < 8; ++n) {
      const float e = __expf(acc[n][i] - mm);
      acc[n][i] = e;                 // keep exp(s - mm) for p
      sum += e;
    }
    sum += __shfl_xor(sum, 1);
    sum += __shfl_xor(sum, 2);
    sum += __shfl_xor(sum, 4);
    sum += __shfl_xor(sum, 8);
    lse4[i] = mm + logf(sum);
    const float rinv = __builtin_amdgcn_rcpf(sum);   // p = exp(s-mm)/sum
#pragma unroll
    for (int n = 0; n < 8; ++n) acc[n][i] *= rinv;
  }

  __syncthreads();  // kb reads done -> overwrite with ps

#pragma unroll
  for (int i = 0; i < 4; ++i) {
    const int q = 16 * w + 4 * g + i;
#pragma unroll
    for (int n = 0; n < 8; ++n)
      kbps[q * 136 + 16 * n + r16] = f2b(acc[n][i]);
  }
  if (r16 == 0) {
#pragma unroll
    for (int i = 0; i < 4; ++i) {
      const int q = 16 * w + 4 * g + i;
      slogits[((size_t)b * SS + st[q]) * HH + h] = lse4[i];
    }
  }
  __syncthreads();

  f32x4 o[4];
#pragma unroll
  for (int n = 0; n < 4; ++n) o[n] = (f32x4){0.f, 0.f, 0.f, 0.f};
#pragma unroll
  for (int kk = 0; kk < 4; ++kk) {
    bf16x8 pa = *(const bf16x8*)&kbps[(16 * w + r16) * 136 + kk * 32 + g * 8];
#pragma unroll
    for (int n = 0; n < 4; ++n) {
      bf16x8 vbf = *(const bf16x8*)&vt[16 * n + r16][kk * 32 + g * 8];
      o[n] = __builtin_amdgcn_mfma_f32_16x16x32_bf16(pa, vbf, o[n], 0, 0, 0);
    }
  }

  __syncthreads();  // ps reads done -> overwrite with ob
#pragma unroll
  for (int i = 0; i < 4; ++i) {
    const int q = 16 * w + 4 * g + i;
#pragma unroll
    for (int n = 0; n < 4; ++n)
      kbps[q * 72 + 16 * n + r16] = f2b(o[n][i]);
  }
  __syncthreads();

  {
    const int row = tid >> 2, q4 = tid & 3;
    uint4 x0 = *(uint4*)&kbps[row * 72 + q4 * 16];
    uint4 x1 = *(uint4*)&kbps[row * 72 + q4 * 16 + 8];
    unsigned short* dst = so + (((size_t)bl * SS + st[row]) * HH + h) * DD + q4 * 16;
    *(uint4*)&dst[0] = x0;
    *(uint4*)&dst[8] = x1;
  }
}

// ---------------------------------------------------------------------------
// Kernel 4: combine — out[b,t] = sum_h w_h * o_h[b,t,h], w_h = exp(l_h-m)/sum.
// ---------------------------------------------------------------------------
__global__ __launch_bounds__(256) void gather_out_kernel(const unsigned short* __restrict__ so,
                                                         const float* __restrict__ slogits,
                                                         float* __restrict__ out,
                                                         const int b_base) {
  const int idx = blockIdx.x * 256 + threadIdx.x;
  const int seg = idx & 7;
  const int btl = idx >> 3;

  const float* lrow = slogits + ((size_t)b_base * SS + btl) * HH;
  float4 l0 = ((const float4*)lrow)[0];
  float4 l1 = ((const float4*)lrow)[1];
  float l[8] = {l0.x, l0.y, l0.z, l0.w, l1.x, l1.y, l1.z, l1.w};
  float m = -3.4e38f;
#pragma unroll
  for (int h = 0; h < HH; ++h) m = fmaxf(m, l[h]);
  float ex[8];
  float sum = 0.f;
#pragma unroll
  for (int h = 0; h < HH; ++h) {
    ex[h] = __expf(l[h] - m);
    sum += ex[h];
  }
  const float rinv = __builtin_amdgcn_rcpf(sum);

  float acc[8];
#pragma unroll
  for (int k = 0; k < 8; ++k) acc[k] = 0.f;
#pragma unroll
  for (int h = 0; h < HH; ++h) {
    const float wgt = ex[h] * rinv;
    uint4 u = *(const uint4*)(so + ((size_t)btl * HH + h) * DD + seg * 8);
    const unsigned int uu[4] = {u.x, u.y, u.z, u.w};
#pragma unroll
    for (int k = 0; k < 4; ++k) {
      acc[2 * k] += wgt * b2f((unsigned short)(uu[k] & 0xffffu));
      acc[2 * k + 1] += wgt * b2f((unsigned short)(uu[k] >> 16));
    }
  }
  float* dst = out + ((size_t)b_base * SS + btl) * DD + seg * 8;
  float4 o0, o1;
  o0.x = acc[0]; o0.y = acc[1]; o0.z = acc[2]; o0.w = acc[3];
  o1.x = acc[4]; o1.y = acc[5]; o1.z = acc[6]; o1.w = acc[7];
  ((float4*)dst)[0] = o0;
  ((float4*)dst)[1] = o1;
}

// ---------------------------------------------------------------------------
extern "C" void kernel_launch(void* const* d_in, const int* in_sizes, int n_in,
                              void* d_out, int out_size, void* d_ws, size_t ws_size,
                              hipStream_t stream) {
  (void)in_sizes; (void)n_in; (void)out_size;
  const float* qk = (const float*)d_in[0];
  const float* v = (const float*)d_in[1];
  const float* rot = (const float*)d_in[2];
  float* out = (float*)d_out;

  char* ws = (char*)d_ws;
  int* sticker = (int*)ws;                                              // @0,          2 MB
  float* slogits = (float*)(ws + ((size_t)2 << 20));                    // @2M,         2 MB
  float* snorm = (float*)(ws + ((size_t)4 << 20));                      // @4M,       256 KB
  unsigned char* bucket = (unsigned char*)(ws + ((size_t)4 << 20) + ((size_t)256 << 10));  // 512 KB
  float* rotT = (float*)(ws + ((size_t)4 << 20) + ((size_t)768 << 10)); // @4M+768K,  128 KB
  unsigned short* rhiT = (unsigned short*)(ws + ((size_t)4 << 20) + ((size_t)896 << 10));  // 64 KB
  unsigned short* rloT = (unsigned short*)(ws + ((size_t)4 << 20) + ((size_t)960 << 10));  // 64 KB
  unsigned short* qhat = (unsigned short*)(ws + ((size_t)5 << 20));     // @5M,         8 MB
  unsigned short* vb = (unsigned short*)(ws + ((size_t)13 << 20));      // @13M,        8 MB
  unsigned short* qhi = (unsigned short*)(ws + ((size_t)21 << 20));     // @21M,        8 MB
  unsigned short* qlo = (unsigned short*)(ws + ((size_t)29 << 20));     // @29M,        8 MB
  unsigned short* so = (unsigned short*)(ws + ((size_t)37 << 20));      // @37M, 32 or 64 MB

  rott_kernel<<<8, 256, 0, stream>>>(rot, rotT, rhiT, rloT);
  prep_kernel<<<(BB * SS * 8) / 256, 256, 0, stream>>>(qk, v, qhat, vb, qhi, qlo, snorm);
  hash_kernel<<<dim3(512, 1, 2), 256, 0, stream>>>(qk, rotT, qhi, qlo, rhiT, rloT, bucket);
  sort_kernel<<<BB * HH, 1024, 0, stream>>>(bucket, sticker);

  const size_t need_full = ((size_t)37 << 20) + (size_t)BB * SS * HH * DD * 2;
  if (ws_size >= need_full) {
    attn_kernel<<<dim3(BB, NB, HH), 256, 0, stream>>>(qhat, vb, snorm, sticker, so, slogits, 0);
    gather_out_kernel<<<(BB * SS * 8) / 256, 256, 0, stream>>>(so, slogits, out, 0);
  } else {
    for (int half = 0; half < 2; ++half) {
      const int b_base = half * (BB / 2);
      attn_kernel<<<dim3(BB / 2, NB, HH), 256, 0, stream>>>(qhat, vb, snorm, sticker, so, slogits, b_base);
      gather_out_kernel<<<(BB / 2 * SS * 8) / 256, 256, 0, stream>>>(so, slogits, out, b_base);
    }
  }
}